// Round 1
// baseline (115.286 us; speedup 1.0000x reference)
//
#include <hip/hip_runtime.h>
#include <hip/hip_bf16.h>

// Sizes fixed by the problem
#define HID   512
#define BB    32
#define NN    96
#define M_TOT (BB * NN)          // 3072 rows of X flattened
// tanh(x) = 1 - 2/(exp2(C*x)+1), C = 2*log2(e)
#define C_TANH 2.8853900817779268f

typedef __attribute__((ext_vector_type(4))) float  f32x4;
typedef __attribute__((ext_vector_type(8))) short  short8;

// ---------------------------------------------------------------------------
// K1: fp32 -> bf16 conversion (RNE), vectorized float4 -> 4x bf16
// ---------------------------------------------------------------------------
static __device__ inline unsigned short f2bf(float x) {
    unsigned int u = __builtin_bit_cast(unsigned int, x);
    u = (u + 0x7FFFu + ((u >> 16) & 1u)) >> 16;   // round-to-nearest-even
    return (unsigned short)u;
}

__global__ __launch_bounds__(256) void cvt_bf16(const float* __restrict__ src,
                                                unsigned short* __restrict__ dst,
                                                int n4) {
    int i = blockIdx.x * 256 + threadIdx.x;
    if (i < n4) {
        f32x4 f = *(const f32x4*)(src + i * 4);
        ushort4 o;
        o.x = f2bf(f[0]); o.y = f2bf(f[1]); o.z = f2bf(f[2]); o.w = f2bf(f[3]);
        *(ushort4*)(dst + i * 4) = o;
    }
}

// ---------------------------------------------------------------------------
// K2: bf16 MFMA GEMM.  Out[m, n] = sum_h X[m,h] * Wrow(n)[h]
//   n < 512 : Wrow = W1 row n,     cols 0..511   -> Ha' = C * out
//   n >= 512: Wrow = W1 row n-512, cols 512..1023-> Hb'' = C * (out + b1[n-512])
// Block = 256 thr = 4 waves; block tile 64(M) x 64(N); wave: 16(M) x 64(N).
// mfma_f32_16x16x32_bf16: A lane l holds A[l&15][(l>>4)*8 + e], e=0..7
//                         B lane l holds B[(l>>4)*8 + e][l&15]
//                         D lane l holds D[(l>>4)*4 + q][l&15], q=0..3
// ---------------------------------------------------------------------------
__global__ __launch_bounds__(256) void gemm_h(const unsigned short* __restrict__ Xb,
                                              const unsigned short* __restrict__ Wb,
                                              const float* __restrict__ b1,
                                              float* __restrict__ HA,
                                              float* __restrict__ HB) {
    int bid = blockIdx.x;                 // 768 blocks = 48 (M) x 16 (N)
    int mb  = (bid % 48) * 64;
    int nb  = (bid / 48) * 64;
    int tid = threadIdx.x;
    int w   = tid >> 6;
    int l   = tid & 63;

    int m0   = mb + 16 * w;
    int lr   = l & 15;
    int koff = (l >> 4) * 8;

    const unsigned short* xp = Xb + (m0 + lr) * 512 + koff;

    const unsigned short* wp[4];
    int ncol[4];
#pragma unroll
    for (int t = 0; t < 4; ++t) {
        int n = nb + 16 * t + lr;
        ncol[t] = n;
        // W1 row (n & 511), column offset 0 or 512 depending on half, + koff
        wp[t] = Wb + (n & 511) * 1024 + ((n >> 9) << 9) + koff;
    }

    f32x4 acc[4] = {};

    for (int k0 = 0; k0 < 512; k0 += 32) {
        short8 a = *(const short8*)(xp + k0);
#pragma unroll
        for (int t = 0; t < 4; ++t) {
            short8 bf = *(const short8*)(wp[t] + k0);
            acc[t] = __builtin_amdgcn_mfma_f32_16x16x32_bf16(a, bf, acc[t], 0, 0, 0);
        }
    }

    int r0 = (l >> 4) * 4;
#pragma unroll
    for (int t = 0; t < 4; ++t) {
        int n = ncol[t];
#pragma unroll
        for (int q = 0; q < 4; ++q) {
            int m = m0 + r0 + q;
            float v = acc[t][q];
            if (n < 512) {
                HA[m * 512 + n] = v * C_TANH;
            } else {
                HB[m * 512 + (n - 512)] = (v + b1[n - 512]) * C_TANH;
            }
        }
    }
}

// ---------------------------------------------------------------------------
// K3: out[b,i,j] = sum_k w2[k] * tanh_from(Ha'[b,i,k] + Hb''[b,j,k]) + b2
// Block: one (b, 16-i-tile, 16-j-tile); 256 thr, thread -> one (i,j) pair.
// LDS: 16 rows A + 16 rows H, 512 f32 each (2KB rows), XOR-swizzled in 16B
// chunks (chunk c stored at c ^ (row&7)) -> j-reads (stride 2048B) become
// <=2-way bank conflicts (free) instead of 16-way.
// ---------------------------------------------------------------------------
__global__ __launch_bounds__(256) void arc_kernel(const float* __restrict__ HA,
                                                  const float* __restrict__ HB,
                                                  const float* __restrict__ w2,
                                                  const float* __restrict__ b2,
                                                  float* __restrict__ out) {
    __shared__ float a_s[16 * 512];   // 32 KB
    __shared__ float h_s[16 * 512];   // 32 KB

    int bid = blockIdx.x;             // 32 * 6 * 6 = 1152
    int b   = bid / 36;
    int it  = (bid % 36) / 6;
    int jt  = bid % 6;
    int tid = threadIdx.x;

    const float* asrc = HA + (b * NN + it * 16) * 512;
    const float* hsrc = HB + (b * NN + jt * 16) * 512;

    // stage 16x512 f32 per array: 2048 float4 chunks each
    for (int idx = tid; idx < 2048; idx += 256) {
        int row = idx >> 7;           // 0..15
        int c   = idx & 127;          // 16B chunk within row
        int cs  = c ^ (row & 7);      // swizzled slot
        f32x4 va = *(const f32x4*)(asrc + row * 512 + c * 4);
        f32x4 vh = *(const f32x4*)(hsrc + row * 512 + c * 4);
        *(f32x4*)(a_s + row * 512 + cs * 4) = va;
        *(f32x4*)(h_s + row * 512 + cs * 4) = vh;
    }
    __syncthreads();

    int ty = tid >> 4;                // i within tile
    int tx = tid & 15;                // j within tile
    const float* arow = a_s + ty * 512;
    const float* hrow = h_s + tx * 512;
    int sa = ty & 7;
    int sh = tx & 7;

    float acc = 0.f;
#pragma unroll 2
    for (int c = 0; c < 128; ++c) {
        f32x4 av = *(const f32x4*)(arow + (c ^ sa) * 4);
        f32x4 hv = *(const f32x4*)(hrow + (c ^ sh) * 4);
        f32x4 wv = *(const f32x4*)(w2 + c * 4);    // uniform -> s_load
#pragma unroll
        for (int e = 0; e < 4; ++e) {
            float x  = av[e] + hv[e];              // already scaled by 2*log2(e)
            float ex = exp2f(x);                   // v_exp_f32
            float r  = __builtin_amdgcn_rcpf(ex + 1.0f);
            float t  = __builtin_fmaf(-2.0f, r, 1.0f);   // tanh
            acc = __builtin_fmaf(wv[e], t, acc);
        }
    }

    int i = it * 16 + ty;
    int j = jt * 16 + tx;
    out[(b * NN + i) * NN + j] = acc + b2[0];
}

// ---------------------------------------------------------------------------
extern "C" void kernel_launch(void* const* d_in, const int* in_sizes, int n_in,
                              void* d_out, int out_size, void* d_ws, size_t ws_size,
                              hipStream_t stream) {
    (void)in_sizes; (void)n_in; (void)out_size; (void)ws_size;

    const float* X  = (const float*)d_in[0];   // (32, 96, 512)
    const float* W1 = (const float*)d_in[1];   // (512, 1024)
    const float* b1 = (const float*)d_in[2];   // (512,)
    const float* W2 = (const float*)d_in[3];   // (1, 512)
    const float* b2 = (const float*)d_in[4];   // (1,)
    float* out = (float*)d_out;                // (32, 96, 96)

    char* ws = (char*)d_ws;
    unsigned short* Xb = (unsigned short*)(ws);              // 3,145,728 B
    unsigned short* Wb = (unsigned short*)(ws + 3145728);    // 1,048,576 B
    float* HA = (float*)(ws + 4194304);                      // 6,291,456 B
    float* HB = (float*)(ws + 10485760);                     // 6,291,456 B (end 16 MB)

    // K1: convert X (393216 float4) and W1 (131072 float4) to bf16
    cvt_bf16<<<1536, 256, 0, stream>>>(X,  Xb, 393216);
    cvt_bf16<<<512,  256, 0, stream>>>(W1, Wb, 131072);

    // K2: H GEMMs (3072 x 1024 x 512), scaled + bias folded
    gemm_h<<<768, 256, 0, stream>>>(Xb, Wb, b1, HA, HB);

    // K3: tanh-dot over 16x16 (i,j) tiles
    arc_kernel<<<1152, 256, 0, stream>>>(HA, HB, W2, b2, out);
}

// Round 3
// 88.091 us; speedup vs baseline: 1.3087x; 1.3087x over previous
//
#include <hip/hip_runtime.h>
#include <hip/hip_bf16.h>

// Sizes fixed by the problem
#define HID   512
#define BB    32
#define NN    96
#define M_TOT (BB * NN)          // 3072 rows of X flattened
// tanh(x) = 1 - 2/(exp2(C*x)+1), C = 2*log2(e)
#define C_TANH 2.8853900817779268f

typedef __attribute__((ext_vector_type(4))) float    f32x4;
typedef __attribute__((ext_vector_type(8))) short    short8;
typedef __attribute__((ext_vector_type(8))) _Float16 half8;

// ---------------------------------------------------------------------------
// K1: fp32 -> bf16 conversion (RNE) for X and W1, one launch.
// ---------------------------------------------------------------------------
static __device__ inline unsigned short f2bf(float x) {
    unsigned int u = __builtin_bit_cast(unsigned int, x);
    u = (u + 0x7FFFu + ((u >> 16) & 1u)) >> 16;   // round-to-nearest-even
    return (unsigned short)u;
}

#define N4_X 393216   // X floats/4
#define N4_W 131072   // W1 floats/4

__global__ __launch_bounds__(256) void cvt_all(const float* __restrict__ X,
                                               const float* __restrict__ W1,
                                               unsigned short* __restrict__ Xb,
                                               unsigned short* __restrict__ Wb) {
    int i = blockIdx.x * 256 + threadIdx.x;
    const float* src;
    unsigned short* dst;
    int k;
    if (i < N4_X) { src = X;  dst = Xb; k = i; }
    else          { src = W1; dst = Wb; k = i - N4_X; if (k >= N4_W) return; }
    f32x4 f = *(const f32x4*)(src + k * 4);
    ushort4 o;
    o.x = f2bf(f[0]); o.y = f2bf(f[1]); o.z = f2bf(f[2]); o.w = f2bf(f[3]);
    *(ushort4*)(dst + k * 4) = o;
}

// ---------------------------------------------------------------------------
// K2: bf16 MFMA GEMM + exp epilogue.
//   n < 512 : Ea[m, n]     = fp16( 2^( C * (X·W1row_n)[cols 0:512] ) )
//   n >= 512: Eh[m, n-512] = fp16( 2^( C * ((X·W1row_{n-512})[cols 512:] + b1) ) )
// Block = 256 thr = 4 waves; block tile 64(M) x 64(N); wave: 16(M) x 64(N).
// mfma_f32_16x16x32_bf16: D lane l holds D[(l>>4)*4 + q][l&15], q=0..3
// ---------------------------------------------------------------------------
__global__ __launch_bounds__(256) void gemm_h(const unsigned short* __restrict__ Xb,
                                              const unsigned short* __restrict__ Wb,
                                              const float* __restrict__ b1,
                                              _Float16* __restrict__ Ea,
                                              _Float16* __restrict__ Eh) {
    int bid = blockIdx.x;                 // 768 blocks = 48 (M) x 16 (N)
    int mb  = (bid % 48) * 64;
    int nb  = (bid / 48) * 64;
    int tid = threadIdx.x;
    int w   = tid >> 6;
    int l   = tid & 63;

    int m0   = mb + 16 * w;
    int lr   = l & 15;
    int koff = (l >> 4) * 8;

    const unsigned short* xp = Xb + (m0 + lr) * 512 + koff;

    const unsigned short* wp[4];
    int ncol[4];
#pragma unroll
    for (int t = 0; t < 4; ++t) {
        int n = nb + 16 * t + lr;
        ncol[t] = n;
        wp[t] = Wb + (n & 511) * 1024 + ((n >> 9) << 9) + koff;
    }

    f32x4 acc[4] = {};

    for (int k0 = 0; k0 < 512; k0 += 32) {
        short8 a = *(const short8*)(xp + k0);
#pragma unroll
        for (int t = 0; t < 4; ++t) {
            short8 bf = *(const short8*)(wp[t] + k0);
            acc[t] = __builtin_amdgcn_mfma_f32_16x16x32_bf16(a, bf, acc[t], 0, 0, 0);
        }
    }

    int r0 = (l >> 4) * 4;
#pragma unroll
    for (int t = 0; t < 4; ++t) {
        int n   = ncol[t];
        int col = n & 511;
        bool isB = (n >= 512);                  // uniform per t
        float bias = isB ? b1[col] : 0.0f;
        _Float16* dst = isB ? Eh : Ea;
#pragma unroll
        for (int q = 0; q < 4; ++q) {
            int m = m0 + r0 + q;
            float arg = (acc[t][q] + bias) * C_TANH;
            dst[m * 512 + col] = (_Float16)exp2f(arg);
        }
    }
}

// ---------------------------------------------------------------------------
// K3: out[b,i,j] = sum_k w2[k] * (1 - 2/(Ea[b,i,k]*Eh[b,j,k] + 1)) + b2
// Tile: 12(i) x 32(j) per block; 192 threads; thread -> (i, j) and (i, j+16).
// 768 blocks = 32b x 8it x 3jt = exactly 3 blocks/CU, 40KB LDS -> 3 resident.
// LDS fp16, XOR-swizzled in 16B chunks (chunk c at c ^ (row&7)):
//   a-read: 4 distinct rows/wave, 16-lane broadcast, conflict-free.
//   h-read: 16 rows/wave, rows r and r+8 share banks -> 2-way (free).
// ---------------------------------------------------------------------------
__global__ __launch_bounds__(192) void arc_kernel(const _Float16* __restrict__ Ea,
                                                  const _Float16* __restrict__ Eh,
                                                  const float* __restrict__ w2,
                                                  const float* __restrict__ b2,
                                                  float* __restrict__ out) {
    __shared__ _Float16 a_s[12 * 512];   // 12 KB
    __shared__ _Float16 h_s[32 * 512];   // 32 KB

    int bid = blockIdx.x;                // 32 * 8 * 3
    int b   = bid / 24;
    int it  = (bid % 24) / 3;
    int jt  = bid % 3;
    int tid = threadIdx.x;

    const _Float16* asrc = Ea + (b * NN + it * 12) * 512;
    const _Float16* hsrc = Eh + (b * NN + jt * 32) * 512;

    // stage a: 12 rows x 64 chunks = 768 (= 4*192); h: 32 x 64 = 2048
    for (int idx = tid; idx < 768; idx += 192) {
        int row = idx >> 6, c = idx & 63, cs = c ^ (row & 7);
        *(f32x4*)(a_s + row * 512 + cs * 8) = *(const f32x4*)(asrc + row * 512 + c * 8);
    }
    for (int idx = tid; idx < 2048; idx += 192) {
        int row = idx >> 6, c = idx & 63, cs = c ^ (row & 7);
        *(f32x4*)(h_s + row * 512 + cs * 8) = *(const f32x4*)(hsrc + row * 512 + c * 8);
    }
    __syncthreads();

    int ty = tid >> 4;                   // 0..11
    int tx = tid & 15;                   // 0..15
    const _Float16* arow  = a_s + ty * 512;
    const _Float16* hrow0 = h_s + tx * 512;
    const _Float16* hrow1 = h_s + (tx + 16) * 512;
    int sa = ty & 7;
    int sh = tx & 7;                     // (tx+16)&7 == tx&7

    float acc0 = 0.f, acc1 = 0.f;
    const half8 ones = {1, 1, 1, 1, 1, 1, 1, 1};

#pragma unroll 2
    for (int c = 0; c < 64; ++c) {
        half8 av = *(const half8*)(arow  + (c ^ sa) * 8);
        half8 h0 = *(const half8*)(hrow0 + (c ^ sh) * 8);
        half8 h1 = *(const half8*)(hrow1 + (c ^ sh) * 8);
        f32x4 wlo = *(const f32x4*)(w2 + c * 8);       // uniform -> s_load
        f32x4 whi = *(const f32x4*)(w2 + c * 8 + 4);

        half8 s0 = av * h0 + ones;       // v_pk_fma_f16
        half8 s1 = av * h1 + ones;
#pragma unroll
        for (int e = 0; e < 8; ++e) {
            float we = (e < 4) ? wlo[e] : whi[e - 4];
            float f0 = (float)s0[e];
            float f1 = (float)s1[e];
            float r0 = __builtin_amdgcn_rcpf(f0);
            float r1 = __builtin_amdgcn_rcpf(f1);
            float t0 = __builtin_fmaf(-2.0f, r0, 1.0f);
            float t1 = __builtin_fmaf(-2.0f, r1, 1.0f);
            acc0 = __builtin_fmaf(we, t0, acc0);
            acc1 = __builtin_fmaf(we, t1, acc1);
        }
    }

    float bb = b2[0];
    int i = it * 12 + ty;
    int row = (b * NN + i) * NN + jt * 32;
    out[row + tx]      = acc0 + bb;
    out[row + tx + 16] = acc1 + bb;
}

// ---------------------------------------------------------------------------
extern "C" void kernel_launch(void* const* d_in, const int* in_sizes, int n_in,
                              void* d_out, int out_size, void* d_ws, size_t ws_size,
                              hipStream_t stream) {
    (void)in_sizes; (void)n_in; (void)out_size; (void)ws_size;

    const float* X  = (const float*)d_in[0];   // (32, 96, 512)
    const float* W1 = (const float*)d_in[1];   // (512, 1024)
    const float* b1 = (const float*)d_in[2];   // (512,)
    const float* W2 = (const float*)d_in[3];   // (1, 512)
    const float* b2 = (const float*)d_in[4];   // (1,)
    float* out = (float*)d_out;                // (32, 96, 96)

    char* ws = (char*)d_ws;
    unsigned short* Xb = (unsigned short*)(ws);              // 3,145,728 B
    unsigned short* Wb = (unsigned short*)(ws + 3145728);    // 1,048,576 B
    _Float16* Ea = (_Float16*)(ws + 4194304);                // 3,145,728 B
    _Float16* Eh = (_Float16*)(ws + 7340032);                // 3,145,728 B (end ~10.5 MB)

    cvt_all<<<2048, 256, 0, stream>>>(X, W1, Xb, Wb);
    gemm_h<<<768, 256, 0, stream>>>(Xb, Wb, b1, Ea, Eh);
    arc_kernel<<<768, 192, 0, stream>>>(Ea, Eh, W2, b2, out);
}

// Round 6
// 58.369 us; speedup vs baseline: 1.9751x; 1.5092x over previous
//
#include <hip/hip_runtime.h>
#include <hip/hip_bf16.h>

#define NN 96
// tanh(x) = 1 - 2/(exp2(C*x)+1), C = 2*log2(e)
#define C_TANH 2.8853900817779268f

typedef __attribute__((ext_vector_type(4))) float    f32x4;
typedef __attribute__((ext_vector_type(8))) short    short8;
typedef __attribute__((ext_vector_type(8))) _Float16 half8;

// v_cvt_pk_bf16_f32: dst.lo16 = bf16(lo), dst.hi16 = bf16(hi), RNE
static __device__ inline unsigned int cvt_pk_bf16(float lo, float hi) {
    unsigned int r;
    asm("v_cvt_pk_bf16_f32 %0, %1, %2" : "=v"(r) : "v"(lo), "v"(hi));
    return r;
}

// ---------------------------------------------------------------------------
// K0: S = b2 + sum_k w2[k]   (single wave)
// ---------------------------------------------------------------------------
__global__ void wsum_kernel(const float* __restrict__ w2,
                            const float* __restrict__ b2,
                            float* __restrict__ S) {
    int t = threadIdx.x;                 // 64
    float s = 0.f;
    for (int k = t; k < 512; k += 64) s += w2[k];
#pragma unroll
    for (int off = 32; off; off >>= 1) s += __shfl_down(s, off, 64);
    if (t == 0) S[0] = s + b2[0];
}

// ---------------------------------------------------------------------------
// K1: fused cvt + bf16 MFMA GEMM + exp epilogue, double-buffered LDS.
//   n < 512 : Ea[m, n]     = fp16( 2^( C * (X·W1row_n)[cols 0:512] ) )
//   n >= 512: Eh[m, n-512] = fp16( 2^( C * ((X·W1row_{n-512})[cols 512:] + b1) ) )
// 768 blocks = 48(M) x 16(N); block tile 64M x 64N; 4 waves, wave = 16M x 64N
// (acc[4] -- wave tile must cover exactly the 64 staged rows; R4's 32M wave
//  tile read LDS rows 64..127 OOB -> NaN).
// Staging converts f32 -> bf16 inline (v_cvt_pk_bf16_f32); 16B chunks are
// XOR-swizzled within each 64B row: chunk cg at cg ^ (row&3).
// ---------------------------------------------------------------------------
__global__ __launch_bounds__(256) void gemm_h(const float* __restrict__ X,
                                              const float* __restrict__ W1,
                                              const float* __restrict__ b1,
                                              _Float16* __restrict__ Ea,
                                              _Float16* __restrict__ Eh) {
    __shared__ unsigned short As[2][2048];   // 4KB each buffer
    __shared__ unsigned short Bs[2][2048];

    int bid = blockIdx.x;
    int mb  = (bid % 48) * 64;
    int nb  = (bid / 48) * 64;
    int tid = threadIdx.x;
    int w   = tid >> 6;
    int l   = tid & 63;

    // staging geometry: thread -> (row 0..63, 8-f32 group 0..3)
    int srow = tid >> 2;
    int sg   = (tid & 3) * 8;
    int scs  = sg ^ ((srow & 3) << 3);       // swizzled short offset in row
    const float* asrc = X + (mb + srow) * 512 + sg;
    int nrow = nb + srow;
    const float* bsrc = W1 + (nrow & 511) * 1024 + ((nrow >> 9) << 9) + sg;
    unsigned short* adst = &As[0][srow * 32 + scs];
    unsigned short* bdst = &Bs[0][srow * 32 + scs];

#define STAGE(buf, k0)                                                        \
    {                                                                         \
        f32x4 a0 = *(const f32x4*)(asrc + (k0));                              \
        f32x4 a1 = *(const f32x4*)(asrc + (k0) + 4);                          \
        f32x4 b0 = *(const f32x4*)(bsrc + (k0));                              \
        f32x4 b4 = *(const f32x4*)(bsrc + (k0) + 4);                          \
        uint4 ua, ub;                                                         \
        ua.x = cvt_pk_bf16(a0[0], a0[1]); ua.y = cvt_pk_bf16(a0[2], a0[3]);   \
        ua.z = cvt_pk_bf16(a1[0], a1[1]); ua.w = cvt_pk_bf16(a1[2], a1[3]);   \
        ub.x = cvt_pk_bf16(b0[0], b0[1]); ub.y = cvt_pk_bf16(b0[2], b0[3]);   \
        ub.z = cvt_pk_bf16(b4[0], b4[1]); ub.w = cvt_pk_bf16(b4[2], b4[3]);   \
        *(uint4*)(adst + (buf) * 2048) = ua;                                  \
        *(uint4*)(bdst + (buf) * 2048) = ub;                                  \
    }

    int lr    = l & 15;
    int koffs = ((l >> 4) * 8) ^ ((lr & 3) << 3);   // swizzled k-chunk
    int aoff  = (16 * w + lr) * 32 + koffs;         // (16w+lr)&3 == lr&3
    int boff0 = lr * 32 + koffs;                    // + t*512 for frag t

    f32x4 acc[4] = {};

#define COMPUTE(cur)                                                          \
    {                                                                         \
        short8 afr = *(const short8*)(&As[cur][aoff]);                        \
        short8 bfr[4];                                                        \
        _Pragma("unroll")                                                     \
        for (int t = 0; t < 4; ++t)                                           \
            bfr[t] = *(const short8*)(&Bs[cur][boff0 + t * 512]);             \
        _Pragma("unroll")                                                     \
        for (int t = 0; t < 4; ++t)                                           \
            acc[t] = __builtin_amdgcn_mfma_f32_16x16x32_bf16(afr, bfr[t],     \
                                                             acc[t], 0, 0, 0);\
    }

    STAGE(0, 0)
#pragma unroll 2
    for (int k = 0; k < 15; ++k) {
        __syncthreads();
        STAGE((k + 1) & 1, (k + 1) * 32)
        COMPUTE(k & 1)
    }
    __syncthreads();
    COMPUTE(1)
#undef STAGE
#undef COMPUTE

    // epilogue: D lane l -> D[(l>>4)*4+q][l&15]
    int r0 = (l >> 4) * 4;
    bool isB = (nb >= 512);                 // uniform per block
    int colbase = nb & 511;
    _Float16* dst = isB ? Eh : Ea;
#pragma unroll
    for (int t = 0; t < 4; ++t) {
        int col = colbase + 16 * t + lr;
        float bias = isB ? b1[col] : 0.0f;
#pragma unroll
        for (int q = 0; q < 4; ++q) {
            int m = mb + 16 * w + r0 + q;
            float arg = (acc[t][q] + bias) * C_TANH;
            dst[m * 512 + col] = (_Float16)exp2f(arg);
        }
    }
}

// ---------------------------------------------------------------------------
// K2: out[b,i,j] = S - 2 * sum_k w2[k] / (Ea[b,i,k]*Eh[b,j,k] + 1)
// Block: 512 thr (8 waves), tile 8i x 16j, split-k=4 within each wave.
// Lane: ty = wave = i-row; tx = j (0..15); kq = k-quarter (0..3).
// 2304 blocks (32b x 12it x 6jt); 26KB LDS -> 4 blocks = 32 waves/CU.
// LDS fp16, 16B chunks swizzled: slot = c ^ (row&7) ^ ((c>>4)<<1).
//   (the (c>>4)<<1 term spreads the 4 kq groups -- chunks 16 apart are 256B
//    apart = same banks without it)
// kq-reduce via shfl_xor(16/32).
// ---------------------------------------------------------------------------
__global__ __launch_bounds__(512) void arc_kernel(const _Float16* __restrict__ Ea,
                                                  const _Float16* __restrict__ Eh,
                                                  const float* __restrict__ w2,
                                                  const float* __restrict__ S,
                                                  float* __restrict__ out) {
    __shared__ _Float16 a_s[8 * 512];    // 8 KB
    __shared__ _Float16 h_s[16 * 512];   // 16 KB
    __shared__ float    w2s[512];        // 2 KB

    int bid = blockIdx.x;                // 32 * 12 * 6
    int b   = bid / 72;
    int it  = (bid % 72) / 6;
    int jt  = bid % 6;
    int tid = threadIdx.x;

    const _Float16* asrc = Ea + (b * NN + it * 8) * 512;
    const _Float16* hsrc = Eh + (b * NN + jt * 16) * 512;

    {   // stage a: 8 rows x 64 chunks = 512
        int row = tid >> 6, c = tid & 63;
        int cs = c ^ (row & 7) ^ ((c >> 4) << 1);
        *(f32x4*)(a_s + row * 512 + cs * 8) = *(const f32x4*)(asrc + row * 512 + c * 8);
    }
#pragma unroll
    for (int k = 0; k < 2; ++k) {        // stage h: 16 x 64 = 1024
        int idx = tid + k * 512;
        int row = idx >> 6, c = idx & 63;
        int cs = c ^ (row & 7) ^ ((c >> 4) << 1);
        *(f32x4*)(h_s + row * 512 + cs * 8) = *(const f32x4*)(hsrc + row * 512 + c * 8);
    }
    if (tid < 128) {                     // stage w2: f32x4 group g at g^((g>>5)<<1)
        int g = tid, gs = g ^ (((g >> 5) & 3) << 1);
        *(f32x4*)(w2s + gs * 4) = *(const f32x4*)(w2 + g * 4);
    }
    __syncthreads();

    int ty = tid >> 6;                   // 0..7  (wave = i-row)
    int kq = (tid >> 4) & 3;             // k-quarter
    int tx = tid & 15;                   // j
    const _Float16* arow = a_s + ty * 512;
    const _Float16* hrow = h_s + tx * 512;
    int sxa = (kq << 4) ^ (kq << 1) ^ (ty & 7);   // chunk = c0 ^ sxa
    int sxh = (kq << 4) ^ (kq << 1) ^ (tx & 7);
    int wqx = (kq << 5) ^ (kq << 1);              // f32x4 group = (c0<<1)^wqx (^1)

    float acc0 = 0.f, acc1 = 0.f;
    const half8 ones = {1, 1, 1, 1, 1, 1, 1, 1};

#pragma unroll
    for (int c0 = 0; c0 < 16; ++c0) {
        half8 av = *(const half8*)(arow + ((c0 ^ sxa) << 3));
        half8 hv = *(const half8*)(hrow + ((c0 ^ sxh) << 3));
        int g0 = ((c0 << 1) ^ wqx);
        f32x4 wlo = *(const f32x4*)(w2s + g0 * 4);
        f32x4 whi = *(const f32x4*)(w2s + (g0 ^ 1) * 4);
        half8 s = av * hv + ones;        // v_pk_fma_f16
#pragma unroll
        for (int e = 0; e < 8; ++e) {
            float we = (e < 4) ? wlo[e] : whi[e - 4];
            float f  = (float)s[e];
            float r  = __builtin_amdgcn_rcpf(f);
            if (e & 1) acc1 = __builtin_fmaf(we, r, acc1);
            else       acc0 = __builtin_fmaf(we, r, acc0);
        }
    }
    float acc = acc0 + acc1;
    acc += __shfl_xor(acc, 16, 64);
    acc += __shfl_xor(acc, 32, 64);

    if (kq == 0) {
        int i = it * 8 + ty;
        int j = jt * 16 + tx;
        out[(b * NN + i) * NN + j] = __builtin_fmaf(-2.f, acc, S[0]);
    }
}

// ---------------------------------------------------------------------------
extern "C" void kernel_launch(void* const* d_in, const int* in_sizes, int n_in,
                              void* d_out, int out_size, void* d_ws, size_t ws_size,
                              hipStream_t stream) {
    (void)in_sizes; (void)n_in; (void)out_size; (void)ws_size;

    const float* X  = (const float*)d_in[0];   // (32, 96, 512)
    const float* W1 = (const float*)d_in[1];   // (512, 1024)
    const float* b1 = (const float*)d_in[2];   // (512,)
    const float* W2 = (const float*)d_in[3];   // (1, 512)
    const float* b2 = (const float*)d_in[4];   // (1,)
    float* out = (float*)d_out;                // (32, 96, 96)

    char* ws = (char*)d_ws;
    _Float16* Ea = (_Float16*)(ws);                // 3,145,728 B
    _Float16* Eh = (_Float16*)(ws + 3145728);      // 3,145,728 B
    float*    S  = (float*)(ws + 6291456);         // 4 B

    wsum_kernel<<<1, 64, 0, stream>>>(W2, b2, S);
    gemm_h<<<768, 256, 0, stream>>>(X, W1, b1, Ea, Eh);
    arc_kernel<<<2304, 512, 0, stream>>>(Ea, Eh, W2, S, out);
}

// Round 7
// 48.396 us; speedup vs baseline: 2.3821x; 1.2061x over previous
//
#include <hip/hip_runtime.h>
#include <hip/hip_bf16.h>

#define NN 96
// tanh(x) = 1 - 2/(exp2(C*x)+1), C = 2*log2(e)
#define C_TANH 2.8853900817779268f

typedef __attribute__((ext_vector_type(4))) float    f32x4;
typedef __attribute__((ext_vector_type(2))) float    f32x2;
typedef __attribute__((ext_vector_type(8))) short    short8;
typedef __attribute__((ext_vector_type(8))) _Float16 half8;

// v_cvt_pk_bf16_f32: dst.lo16 = bf16(lo), dst.hi16 = bf16(hi), RNE
static __device__ inline unsigned int cvt_pk_bf16(float lo, float hi) {
    unsigned int r;
    asm("v_cvt_pk_bf16_f32 %0, %1, %2" : "=v"(r) : "v"(lo), "v"(hi));
    return r;
}

// ---------------------------------------------------------------------------
// K0: S = b2 + sum_k w2[k]   (single wave)
// ---------------------------------------------------------------------------
__global__ void wsum_kernel(const float* __restrict__ w2,
                            const float* __restrict__ b2,
                            float* __restrict__ S) {
    int t = threadIdx.x;                 // 64
    float s = 0.f;
    for (int k = t; k < 512; k += 64) s += w2[k];
#pragma unroll
    for (int off = 32; off; off >>= 1) s += __shfl_down(s, off, 64);
    if (t == 0) S[0] = s + b2[0];
}

// ---------------------------------------------------------------------------
// K1: fused cvt + bf16 MFMA GEMM + exp epilogue, double-buffered LDS.
// (unchanged from R6 -- passed at 58 µs total)
// ---------------------------------------------------------------------------
__global__ __launch_bounds__(256) void gemm_h(const float* __restrict__ X,
                                              const float* __restrict__ W1,
                                              const float* __restrict__ b1,
                                              _Float16* __restrict__ Ea,
                                              _Float16* __restrict__ Eh) {
    __shared__ unsigned short As[2][2048];   // 4KB each buffer
    __shared__ unsigned short Bs[2][2048];

    int bid = blockIdx.x;
    int mb  = (bid % 48) * 64;
    int nb  = (bid / 48) * 64;
    int tid = threadIdx.x;
    int w   = tid >> 6;
    int l   = tid & 63;

    int srow = tid >> 2;
    int sg   = (tid & 3) * 8;
    int scs  = sg ^ ((srow & 3) << 3);       // swizzled short offset in row
    const float* asrc = X + (mb + srow) * 512 + sg;
    int nrow = nb + srow;
    const float* bsrc = W1 + (nrow & 511) * 1024 + ((nrow >> 9) << 9) + sg;
    unsigned short* adst = &As[0][srow * 32 + scs];
    unsigned short* bdst = &Bs[0][srow * 32 + scs];

#define STAGE(buf, k0)                                                        \
    {                                                                         \
        f32x4 a0 = *(const f32x4*)(asrc + (k0));                              \
        f32x4 a1 = *(const f32x4*)(asrc + (k0) + 4);                          \
        f32x4 b0 = *(const f32x4*)(bsrc + (k0));                              \
        f32x4 b4 = *(const f32x4*)(bsrc + (k0) + 4);                          \
        uint4 ua, ub;                                                         \
        ua.x = cvt_pk_bf16(a0[0], a0[1]); ua.y = cvt_pk_bf16(a0[2], a0[3]);   \
        ua.z = cvt_pk_bf16(a1[0], a1[1]); ua.w = cvt_pk_bf16(a1[2], a1[3]);   \
        ub.x = cvt_pk_bf16(b0[0], b0[1]); ub.y = cvt_pk_bf16(b0[2], b0[3]);   \
        ub.z = cvt_pk_bf16(b4[0], b4[1]); ub.w = cvt_pk_bf16(b4[2], b4[3]);   \
        *(uint4*)(adst + (buf) * 2048) = ua;                                  \
        *(uint4*)(bdst + (buf) * 2048) = ub;                                  \
    }

    int lr    = l & 15;
    int koffs = ((l >> 4) * 8) ^ ((lr & 3) << 3);   // swizzled k-chunk
    int aoff  = (16 * w + lr) * 32 + koffs;
    int boff0 = lr * 32 + koffs;

    f32x4 acc[4] = {};

#define COMPUTE(cur)                                                          \
    {                                                                         \
        short8 afr = *(const short8*)(&As[cur][aoff]);                        \
        short8 bfr[4];                                                        \
        _Pragma("unroll")                                                     \
        for (int t = 0; t < 4; ++t)                                           \
            bfr[t] = *(const short8*)(&Bs[cur][boff0 + t * 512]);             \
        _Pragma("unroll")                                                     \
        for (int t = 0; t < 4; ++t)                                           \
            acc[t] = __builtin_amdgcn_mfma_f32_16x16x32_bf16(afr, bfr[t],     \
                                                             acc[t], 0, 0, 0);\
    }

    STAGE(0, 0)
#pragma unroll 2
    for (int k = 0; k < 15; ++k) {
        __syncthreads();
        STAGE((k + 1) & 1, (k + 1) * 32)
        COMPUTE(k & 1)
    }
    __syncthreads();
    COMPUTE(1)
#undef STAGE
#undef COMPUTE

    int r0 = (l >> 4) * 4;
    bool isB = (nb >= 512);                 // uniform per block
    int colbase = nb & 511;
    _Float16* dst = isB ? Eh : Ea;
#pragma unroll
    for (int t = 0; t < 4; ++t) {
        int col = colbase + 16 * t + lr;
        float bias = isB ? b1[col] : 0.0f;
#pragma unroll
        for (int q = 0; q < 4; ++q) {
            int m = mb + 16 * w + r0 + q;
            float arg = (acc[t][q] + bias) * C_TANH;
            dst[m * 512 + col] = (_Float16)exp2f(arg);
        }
    }
}

// ---------------------------------------------------------------------------
// K2 v3: out[b,i,j] = S - 2 * sum_k w2[k] / (Ea[b,i,k]*Eh[b,j,k] + 1)
// Tile 16i x 16j per block, 256 thr = 4 waves.
// kq = WAVE index (readfirstlane -> SGPR) => w2 reads are scalar s_loads,
//   no LDS traffic for w2 (was 2 of 4 ds_read_b128 per iter in v2).
// Thread = 2i x 2j x 128k: 4 ds_read_b128 serve 32 products (2x fewer
//   LDS reads per product than v2).
// Pair-rcp: w0/s0 + w1/s1 = (w0*s1+w1*s0)/(s0*s1) -- halves trans-pipe ops.
// s computed as fmaf((float)a,(float)h,1.0f) -> v_fma_mix_f32 (no cvt).
// Cross-wave kq reduction via 3KB LDS; wave 0 writes the 16x16 tile.
// 1152 blocks (32b x 6it x 6jt); LDS 35KB -> 4 blocks/CU resident.
// Swizzle slot = c ^ (row&7): row-pairs (r, r+8) alias -> 2-way only (free).
// ---------------------------------------------------------------------------
__global__ __launch_bounds__(256) void arc_kernel(const _Float16* __restrict__ Ea,
                                                  const _Float16* __restrict__ Eh,
                                                  const float* __restrict__ w2,
                                                  const float* __restrict__ S,
                                                  float* __restrict__ out) {
    __shared__ _Float16 a_s[16 * 512];   // 16 KB
    __shared__ _Float16 h_s[16 * 512];   // 16 KB
    __shared__ float    red[3][64][4];   // 3 KB (waves 1..3 partials)

    int bid = blockIdx.x;                // 32 * 6 * 6
    int b   = bid / 36;
    int it  = (bid % 36) / 6;
    int jt  = bid % 6;
    int tid = threadIdx.x;

    const _Float16* asrc = Ea + (b * NN + it * 16) * 512;
    const _Float16* hsrc = Eh + (b * NN + jt * 16) * 512;

    // stage 16 rows x 64 chunks = 1024 chunks per array, 4 per thread
#pragma unroll
    for (int p = 0; p < 4; ++p) {
        int idx = tid + p * 256;
        int row = idx >> 6, c = idx & 63;
        int cs = c ^ (row & 7);
        *(f32x4*)(a_s + row * 512 + cs * 8) = *(const f32x4*)(asrc + row * 512 + c * 8);
        *(f32x4*)(h_s + row * 512 + cs * 8) = *(const f32x4*)(hsrc + row * 512 + c * 8);
    }
    __syncthreads();

    int w  = tid >> 6;
    int kq = __builtin_amdgcn_readfirstlane(w);   // SGPR 0..3
    int l  = tid & 63;
    int pi = l >> 3;                     // i-pair 0..7
    int pj = l & 7;                      // j-pair 0..7
    int r0a = pi * 2, r1a = r0a + 1;
    int r0h = pj * 2, r1h = r0h + 1;

    const _Float16* a0 = a_s + r0a * 512 + kq * 128;
    const _Float16* a1 = a_s + r1a * 512 + kq * 128;
    const _Float16* h0 = h_s + r0h * 512 + kq * 128;
    const _Float16* h1 = h_s + r1h * 512 + kq * 128;
    int sa0 = r0a & 7, sa1 = r1a & 7, sh0 = r0h & 7, sh1 = r1h & 7;
    const float* wp = w2 + kq * 128;     // uniform -> s_load

    float acc00 = 0.f, acc01 = 0.f, acc10 = 0.f, acc11 = 0.f;

#define PROC(av, hv, acc)                                                     \
    {                                                                         \
        float s0 = __builtin_fmaf((float)av[0], (float)hv[0], 1.0f);          \
        float s1 = __builtin_fmaf((float)av[1], (float)hv[1], 1.0f);          \
        float s2 = __builtin_fmaf((float)av[2], (float)hv[2], 1.0f);          \
        float s3 = __builtin_fmaf((float)av[3], (float)hv[3], 1.0f);          \
        float s4 = __builtin_fmaf((float)av[4], (float)hv[4], 1.0f);          \
        float s5 = __builtin_fmaf((float)av[5], (float)hv[5], 1.0f);          \
        float s6 = __builtin_fmaf((float)av[6], (float)hv[6], 1.0f);          \
        float s7 = __builtin_fmaf((float)av[7], (float)hv[7], 1.0f);          \
        float n0 = __builtin_fmaf(wv1, s0, wv0 * s1);                         \
        float n1 = __builtin_fmaf(wv3, s2, wv2 * s3);                         \
        float n2 = __builtin_fmaf(wv5, s4, wv4 * s5);                         \
        float n3 = __builtin_fmaf(wv7, s6, wv6 * s7);                         \
        acc = __builtin_fmaf(n0, __builtin_amdgcn_rcpf(s0 * s1), acc);        \
        acc = __builtin_fmaf(n1, __builtin_amdgcn_rcpf(s2 * s3), acc);        \
        acc = __builtin_fmaf(n2, __builtin_amdgcn_rcpf(s4 * s5), acc);        \
        acc = __builtin_fmaf(n3, __builtin_amdgcn_rcpf(s6 * s7), acc);        \
    }

#pragma unroll 4
    for (int c = 0; c < 16; ++c) {
        half8 av0 = *(const half8*)(a0 + ((c ^ sa0) << 3));
        half8 av1 = *(const half8*)(a1 + ((c ^ sa1) << 3));
        half8 hv0 = *(const half8*)(h0 + ((c ^ sh0) << 3));
        half8 hv1 = *(const half8*)(h1 + ((c ^ sh1) << 3));
        f32x4 wlo = *(const f32x4*)(wp + c * 8);
        f32x4 whi = *(const f32x4*)(wp + c * 8 + 4);
        float wv0 = wlo[0], wv1 = wlo[1], wv2 = wlo[2], wv3 = wlo[3];
        float wv4 = whi[0], wv5 = whi[1], wv6 = whi[2], wv7 = whi[3];
        PROC(av0, hv0, acc00)
        PROC(av0, hv1, acc01)
        PROC(av1, hv0, acc10)
        PROC(av1, hv1, acc11)
    }
#undef PROC

    if (w != 0) {
        f32x4 v = {acc00, acc01, acc10, acc11};
        *(f32x4*)(&red[w - 1][l][0]) = v;
    }
    __syncthreads();

    if (w == 0) {
#pragma unroll
        for (int r = 0; r < 3; ++r) {
            f32x4 v = *(const f32x4*)(&red[r][l][0]);
            acc00 += v[0]; acc01 += v[1]; acc10 += v[2]; acc11 += v[3];
        }
        float Sv = S[0];
        int i0 = it * 16 + r0a;
        int j0 = jt * 16 + r0h;
        f32x2 o0 = {__builtin_fmaf(-2.f, acc00, Sv), __builtin_fmaf(-2.f, acc01, Sv)};
        f32x2 o1 = {__builtin_fmaf(-2.f, acc10, Sv), __builtin_fmaf(-2.f, acc11, Sv)};
        *(f32x2*)(out + (b * NN + i0) * NN + j0)       = o0;
        *(f32x2*)(out + (b * NN + i0 + 1) * NN + j0)   = o1;
    }
}

// ---------------------------------------------------------------------------
extern "C" void kernel_launch(void* const* d_in, const int* in_sizes, int n_in,
                              void* d_out, int out_size, void* d_ws, size_t ws_size,
                              hipStream_t stream) {
    (void)in_sizes; (void)n_in; (void)out_size; (void)ws_size;

    const float* X  = (const float*)d_in[0];   // (32, 96, 512)
    const float* W1 = (const float*)d_in[1];   // (512, 1024)
    const float* b1 = (const float*)d_in[2];   // (512,)
    const float* W2 = (const float*)d_in[3];   // (1, 512)
    const float* b2 = (const float*)d_in[4];   // (1,)
    float* out = (float*)d_out;                // (32, 96, 96)

    char* ws = (char*)d_ws;
    _Float16* Ea = (_Float16*)(ws);                // 3,145,728 B
    _Float16* Eh = (_Float16*)(ws + 3145728);      // 3,145,728 B
    float*    S  = (float*)(ws + 6291456);         // 4 B

    wsum_kernel<<<1, 64, 0, stream>>>(W2, b2, S);
    gemm_h<<<768, 256, 0, stream>>>(X, W1, b1, Ea, Eh);
    arc_kernel<<<1152, 256, 0, stream>>>(Ea, Eh, W2, S, out);
}

// Round 8
// 35.826 us; speedup vs baseline: 3.2180x; 1.3509x over previous
//
#include <hip/hip_runtime.h>
#include <hip/hip_bf16.h>

#define NN 96
// tanh(x) = 1 - 2/(exp2(C*x)+1), C = 2*log2(e)
#define C_TANH 2.8853900817779268f

typedef __attribute__((ext_vector_type(4))) float    f32x4;
typedef __attribute__((ext_vector_type(2))) float    f32x2;
typedef __attribute__((ext_vector_type(8))) short    short8;
typedef __attribute__((ext_vector_type(8))) _Float16 half8;

// v_cvt_pk_bf16_f32: dst.lo16 = bf16(lo), dst.hi16 = bf16(hi), RNE
static __device__ inline unsigned int cvt_pk_bf16(float lo, float hi) {
    unsigned int r;
    asm("v_cvt_pk_bf16_f32 %0, %1, %2" : "=v"(r) : "v"(lo), "v"(hi));
    return r;
}

// ---------------------------------------------------------------------------
// K1: fused cvt + bf16 MFMA GEMM + exp epilogue.
//   n < 512 : Ea[m, n]     = fp16( 2^( C * (X·W1row_n)[cols 0:512] ) )
//   n >= 512: Eh[m, n-512] = fp16( 2^( C * ((X·W1row_{n-512})[cols 512:] + b1) ) )
// 768 blocks; XCD-swizzle: xcd = bid&7 owns M-rows [xcd*384, +384) x all N.
//   Per-XCD working set = X-chunk 0.77MB + W1 2MB < 4MB L2; all 96 blocks of
//   a chunk co-resident (3 blocks/CU x 32 CU). Cuts ~192MB L3 traffic to
//   ~22MB HBM + L2 hits. arc uses the matching b-partition (b = 4*xcd..).
// T14 async-stage split: RA/RB named register sets ping-pong; global loads
//   issued 2 k-steps ahead, cvt+ds_write 1 step ahead, MFMA between.
// ---------------------------------------------------------------------------
__global__ __launch_bounds__(256) void gemm_h(const float* __restrict__ X,
                                              const float* __restrict__ W1,
                                              const float* __restrict__ b1,
                                              _Float16* __restrict__ Ea,
                                              _Float16* __restrict__ Eh) {
    __shared__ unsigned short As[2][2048];   // 4KB each buffer
    __shared__ unsigned short Bs[2][2048];

    int bid  = blockIdx.x;
    int xcd  = bid & 7;
    int sub  = bid >> 3;                 // 0..95
    int mloc = sub % 6;
    int nq   = sub / 6;                  // 0..15
    int mb   = (xcd * 6 + mloc) * 64;
    int nb   = nq * 64;
    int tid = threadIdx.x;
    int w   = tid >> 6;
    int l   = tid & 63;

    // staging geometry: thread -> (row 0..63, 8-f32 group 0..3)
    int srow = tid >> 2;
    int sg   = (tid & 3) * 8;
    int scs  = sg ^ ((srow & 3) << 3);       // swizzled short offset in row
    const float* asrc = X + (mb + srow) * 512 + sg;
    int nrow = nb + srow;
    const float* bsrc = W1 + (nrow & 511) * 1024 + ((nrow >> 9) << 9) + sg;
    unsigned short* adst = &As[0][srow * 32 + scs];
    unsigned short* bdst = &Bs[0][srow * 32 + scs];

    struct Regs { f32x4 a0, a1, b0, b4; };
    Regs RA, RB;

#define LOADR(R, k0)                                                          \
    {                                                                         \
        R.a0 = *(const f32x4*)(asrc + (k0));                                  \
        R.a1 = *(const f32x4*)(asrc + (k0) + 4);                              \
        R.b0 = *(const f32x4*)(bsrc + (k0));                                  \
        R.b4 = *(const f32x4*)(bsrc + (k0) + 4);                              \
    }
#define WRITER(R, buf)                                                        \
    {                                                                         \
        uint4 ua, ub;                                                         \
        ua.x = cvt_pk_bf16(R.a0[0], R.a0[1]); ua.y = cvt_pk_bf16(R.a0[2], R.a0[3]); \
        ua.z = cvt_pk_bf16(R.a1[0], R.a1[1]); ua.w = cvt_pk_bf16(R.a1[2], R.a1[3]); \
        ub.x = cvt_pk_bf16(R.b0[0], R.b0[1]); ub.y = cvt_pk_bf16(R.b0[2], R.b0[3]); \
        ub.z = cvt_pk_bf16(R.b4[0], R.b4[1]); ub.w = cvt_pk_bf16(R.b4[2], R.b4[3]); \
        *(uint4*)(adst + (buf) * 2048) = ua;                                  \
        *(uint4*)(bdst + (buf) * 2048) = ub;                                  \
    }

    int lr    = l & 15;
    int koffs = ((l >> 4) * 8) ^ ((lr & 3) << 3);   // swizzled k-chunk
    int aoff  = (16 * w + lr) * 32 + koffs;
    int boff0 = lr * 32 + koffs;

    f32x4 acc[4] = {};

#define COMPUTE(cur)                                                          \
    {                                                                         \
        short8 afr = *(const short8*)(&As[cur][aoff]);                        \
        short8 bfr[4];                                                        \
        _Pragma("unroll")                                                     \
        for (int t = 0; t < 4; ++t)                                           \
            bfr[t] = *(const short8*)(&Bs[cur][boff0 + t * 512]);             \
        _Pragma("unroll")                                                     \
        for (int t = 0; t < 4; ++t)                                           \
            acc[t] = __builtin_amdgcn_mfma_f32_16x16x32_bf16(afr, bfr[t],     \
                                                             acc[t], 0, 0, 0);\
    }

    // pipeline: LOADR 2 ahead, WRITER 1 ahead, COMPUTE current
    LOADR(RA, 0)
    WRITER(RA, 0)                         // k=0 -> buf0
    LOADR(RB, 32)                         // k=1 in flight
    __syncthreads();
#pragma unroll 1
    for (int kk = 0; kk < 7; ++kk) {      // k = 2kk, 2kk+1
        LOADR(RA, (2 * kk + 2) * 32)
        COMPUTE(0)                        // k = 2kk
        WRITER(RB, 1)                     // k = 2kk+1 (waits its vmcnt)
        __syncthreads();
        LOADR(RB, (2 * kk + 3) * 32)
        COMPUTE(1)                        // k = 2kk+1
        WRITER(RA, 0)                     // k = 2kk+2
        __syncthreads();
    }
    COMPUTE(0)                            // k = 14
    WRITER(RB, 1)                         // k = 15
    __syncthreads();
    COMPUTE(1)                            // k = 15
#undef LOADR
#undef WRITER
#undef COMPUTE

    // epilogue: D lane l -> D[(l>>4)*4+q][l&15]
    int r0 = (l >> 4) * 4;
    bool isB = (nb >= 512);                 // uniform per block
    int colbase = nb & 511;
    _Float16* dst = isB ? Eh : Ea;
#pragma unroll
    for (int t = 0; t < 4; ++t) {
        int col = colbase + 16 * t + lr;
        float bias = isB ? b1[col] : 0.0f;
#pragma unroll
        for (int q = 0; q < 4; ++q) {
            int m = mb + 16 * w + r0 + q;
            float arg = (acc[t][q] + bias) * C_TANH;
            dst[m * 512 + col] = (_Float16)exp2f(arg);
        }
    }
}

// ---------------------------------------------------------------------------
// K2 v4: out[b,i,j] = S - 2 * sum_k w2[k] / (Ea[b,i,k]*Eh[b,j,k] + 1)
//   S = b2 + sum_k w2[k], computed by wave 0 at the tail (wsum kernel folded).
// Tile 16i x 16j per block, 256 thr = 4 waves; kq = wave index (SGPR) so
// w2 reads are scalar; thread = 2i x 2j x 128k; pair-rcp.
// 1152 blocks; XCD-swizzle: xcd = bid&7 owns b in [4*xcd, +4) -- the same
// rows gemm wrote on that XCD -> Ea/Eh are L2 hits (768KB working set).
// ---------------------------------------------------------------------------
__global__ __launch_bounds__(256) void arc_kernel(const _Float16* __restrict__ Ea,
                                                  const _Float16* __restrict__ Eh,
                                                  const float* __restrict__ w2,
                                                  const float* __restrict__ b2,
                                                  float* __restrict__ out) {
    __shared__ _Float16 a_s[16 * 512];   // 16 KB
    __shared__ _Float16 h_s[16 * 512];   // 16 KB
    __shared__ float    red[3][64][4];   // 3 KB (waves 1..3 partials)

    int bid = blockIdx.x;                // 32 * 6 * 6 = 1152
    int xcd = bid & 7;
    int sub = bid >> 3;                  // 0..143
    int b   = xcd * 4 + sub / 36;
    int r   = sub % 36;
    int it  = r / 6;
    int jt  = r % 6;
    int tid = threadIdx.x;

    const _Float16* asrc = Ea + (b * NN + it * 16) * 512;
    const _Float16* hsrc = Eh + (b * NN + jt * 16) * 512;

    // stage 16 rows x 64 chunks = 1024 chunks per array, 4 per thread
#pragma unroll
    for (int p = 0; p < 4; ++p) {
        int idx = tid + p * 256;
        int row = idx >> 6, c = idx & 63;
        int cs = c ^ (row & 7);
        *(f32x4*)(a_s + row * 512 + cs * 8) = *(const f32x4*)(asrc + row * 512 + c * 8);
        *(f32x4*)(h_s + row * 512 + cs * 8) = *(const f32x4*)(hsrc + row * 512 + c * 8);
    }
    __syncthreads();

    int w  = tid >> 6;
    int kq = __builtin_amdgcn_readfirstlane(w);   // SGPR 0..3
    int l  = tid & 63;
    int pi = l >> 3;                     // i-pair 0..7
    int pj = l & 7;                      // j-pair 0..7
    int r0a = pi * 2, r1a = r0a + 1;
    int r0h = pj * 2, r1h = r0h + 1;

    const _Float16* a0 = a_s + r0a * 512 + kq * 128;
    const _Float16* a1 = a_s + r1a * 512 + kq * 128;
    const _Float16* h0 = h_s + r0h * 512 + kq * 128;
    const _Float16* h1 = h_s + r1h * 512 + kq * 128;
    int sa0 = r0a & 7, sa1 = r1a & 7, sh0 = r0h & 7, sh1 = r1h & 7;
    const float* wp = w2 + kq * 128;     // uniform -> s_load

    float acc00 = 0.f, acc01 = 0.f, acc10 = 0.f, acc11 = 0.f;

#define PROC(av, hv, acc)                                                     \
    {                                                                         \
        float s0 = __builtin_fmaf((float)av[0], (float)hv[0], 1.0f);          \
        float s1 = __builtin_fmaf((float)av[1], (float)hv[1], 1.0f);          \
        float s2 = __builtin_fmaf((float)av[2], (float)hv[2], 1.0f);          \
        float s3 = __builtin_fmaf((float)av[3], (float)hv[3], 1.0f);          \
        float s4 = __builtin_fmaf((float)av[4], (float)hv[4], 1.0f);          \
        float s5 = __builtin_fmaf((float)av[5], (float)hv[5], 1.0f);          \
        float s6 = __builtin_fmaf((float)av[6], (float)hv[6], 1.0f);          \
        float s7 = __builtin_fmaf((float)av[7], (float)hv[7], 1.0f);          \
        float n0 = __builtin_fmaf(wv1, s0, wv0 * s1);                         \
        float n1 = __builtin_fmaf(wv3, s2, wv2 * s3);                         \
        float n2 = __builtin_fmaf(wv5, s4, wv4 * s5);                         \
        float n3 = __builtin_fmaf(wv7, s6, wv6 * s7);                         \
        acc = __builtin_fmaf(n0, __builtin_amdgcn_rcpf(s0 * s1), acc);        \
        acc = __builtin_fmaf(n1, __builtin_amdgcn_rcpf(s2 * s3), acc);        \
        acc = __builtin_fmaf(n2, __builtin_amdgcn_rcpf(s4 * s5), acc);        \
        acc = __builtin_fmaf(n3, __builtin_amdgcn_rcpf(s6 * s7), acc);        \
    }

#pragma unroll 4
    for (int c = 0; c < 16; ++c) {
        half8 av0 = *(const half8*)(a0 + ((c ^ sa0) << 3));
        half8 av1 = *(const half8*)(a1 + ((c ^ sa1) << 3));
        half8 hv0 = *(const half8*)(h0 + ((c ^ sh0) << 3));
        half8 hv1 = *(const half8*)(h1 + ((c ^ sh1) << 3));
        f32x4 wlo = *(const f32x4*)(wp + c * 8);
        f32x4 whi = *(const f32x4*)(wp + c * 8 + 4);
        float wv0 = wlo[0], wv1 = wlo[1], wv2 = wlo[2], wv3 = wlo[3];
        float wv4 = whi[0], wv5 = whi[1], wv6 = whi[2], wv7 = whi[3];
        PROC(av0, hv0, acc00)
        PROC(av0, hv1, acc01)
        PROC(av1, hv0, acc10)
        PROC(av1, hv1, acc11)
    }
#undef PROC

    if (w != 0) {
        f32x4 v = {acc00, acc01, acc10, acc11};
        *(f32x4*)(&red[w - 1][l][0]) = v;
    }
    __syncthreads();

    if (w == 0) {
#pragma unroll
        for (int rr = 0; rr < 3; ++rr) {
            f32x4 v = *(const f32x4*)(&red[rr][l][0]);
            acc00 += v[0]; acc01 += v[1]; acc10 += v[2]; acc11 += v[3];
        }
        // S = b2 + sum(w2): 8 elems/lane + butterfly (all lanes get total)
        f32x4 v0 = *(const f32x4*)(w2 + l * 8);
        f32x4 v1 = *(const f32x4*)(w2 + l * 8 + 4);
        float sv = (v0[0] + v0[1]) + (v0[2] + v0[3])
                 + (v1[0] + v1[1]) + (v1[2] + v1[3]);
#pragma unroll
        for (int off = 32; off; off >>= 1) sv += __shfl_xor(sv, off, 64);
        float Sv = sv + b2[0];

        int i0 = it * 16 + r0a;
        int j0 = jt * 16 + r0h;
        f32x2 o0 = {__builtin_fmaf(-2.f, acc00, Sv), __builtin_fmaf(-2.f, acc01, Sv)};
        f32x2 o1 = {__builtin_fmaf(-2.f, acc10, Sv), __builtin_fmaf(-2.f, acc11, Sv)};
        *(f32x2*)(out + (b * NN + i0) * NN + j0)     = o0;
        *(f32x2*)(out + (b * NN + i0 + 1) * NN + j0) = o1;
    }
}

// ---------------------------------------------------------------------------
extern "C" void kernel_launch(void* const* d_in, const int* in_sizes, int n_in,
                              void* d_out, int out_size, void* d_ws, size_t ws_size,
                              hipStream_t stream) {
    (void)in_sizes; (void)n_in; (void)out_size; (void)ws_size;

    const float* X  = (const float*)d_in[0];   // (32, 96, 512)
    const float* W1 = (const float*)d_in[1];   // (512, 1024)
    const float* b1 = (const float*)d_in[2];   // (512,)
    const float* W2 = (const float*)d_in[3];   // (1, 512)
    const float* b2 = (const float*)d_in[4];   // (1,)
    float* out = (float*)d_out;                // (32, 96, 96)

    char* ws = (char*)d_ws;
    _Float16* Ea = (_Float16*)(ws);                // 3,145,728 B
    _Float16* Eh = (_Float16*)(ws + 3145728);      // 3,145,728 B

    gemm_h<<<768, 256, 0, stream>>>(X, W1, b1, Ea, Eh);
    arc_kernel<<<1152, 256, 0, stream>>>(Ea, Eh, W2, b2, out);
}